// Round 6
// baseline (340.054 us; speedup 1.0000x reference)
//
#include <hip/hip_runtime.h>

// ---------------------------------------------------------------------------
// Self-attention, fp16-MFMA pipeline (R6: double-buffered LDS, 1 barrier/iter):
//   xh   = fp16(x)                        [16384, 768]
//   wT   = fp16(kernel^T per head)        [3][768(o)][768(d)]
//   QKh  = xh @ wT[0..1]^T                [16384, 1536]  (Q | K per row)
//   Vt_b = wT2 @ xh_b^T   (per batch)     [8][768(o)][2048(t)]
//   Ps_b = exp(Q_b@K_b^T/8 - 12)          [8][2048, 2048] f16 (unnormalized)
//          + rowsum atomics -> R[8][2048]
//   out  = (Ps_b @ Vt_b^T) * (1/R[row])   [8][2048, 768]  fp32
//
// GEMM core: C = A @ B^T, 128x128 tile, BK=64, 16x16x32 MFMA, XCD remap,
// XOR-swizzled conflict-free LDS (R5), now DOUBLE-BUFFERED (2 x 32 KB):
//   preload(0) -> buf0
//   iter k: __syncthreads()   // drains loads(k) issued one compute-phase ago
//           issue loads(k+1) -> buf[(k+1)&1]   (fly during compute(k))
//           compute(k) from buf[k&1]
// One barrier per K-iter; the compiler's vmcnt(0)-before-barrier now waits on
// loads that had ~750 cyc of MFMA time to land -> exposed latency ~0.
// ---------------------------------------------------------------------------

typedef _Float16 f16;
typedef _Float16 f16x8 __attribute__((ext_vector_type(8)));
typedef _Float16 f16x4 __attribute__((ext_vector_type(4)));
typedef float f32x4 __attribute__((ext_vector_type(4)));

__device__ __forceinline__ void gload16(const void* g, void* l) {
    __builtin_amdgcn_global_load_lds((__attribute__((address_space(1))) void*)g,
                                     (__attribute__((address_space(3))) void*)l,
                                     16, 0, 0);
}

// MODE 0: C[row,col] = (OutT)acc
// MODE 1: C = f16(exp(acc/8 - 12)); atomicAdd row sums into R[bz*2048+row]
// MODE 2: C = (OutT)(acc / R[bz*2048+row])
template <int MODE, typename OutT>
__global__ __launch_bounds__(256, 2)
void gemm_bt(const f16* __restrict__ A, const f16* __restrict__ B,
             OutT* __restrict__ C, float* R, int K, int lda, int ldb, int ldc,
             long sA, long sB, long sC)
{
    __shared__ __align__(16) f16 lA[2][128 * 64];
    __shared__ __align__(16) f16 lB[2][128 * 64];

    const int tid  = threadIdx.x;
    const int wave = tid >> 6;
    const int lane = tid & 63;

    // XCD-aware remap (bijection when nb % 8 == 0; all our grids qualify)
    const unsigned gx = gridDim.x, gy = gridDim.y;
    const unsigned nb = gx * gy * gridDim.z;
    unsigned lin = blockIdx.x + gx * (blockIdx.y + gy * blockIdx.z);
    if ((nb & 7u) == 0u) lin = (lin & 7u) * (nb >> 3) + (lin >> 3);
    const unsigned bx = lin % gx;
    const unsigned rem = lin / gx;
    const unsigned by = rem % gy;
    const unsigned bz = rem / gy;

    A += (long)bz * sA;
    B += (long)bz * sB;
    C += (long)bz * sC;

    const long row0 = (long)by * 128;
    const long col0 = (long)bx * 128;

    // Staging: pass p (0..3), LDS chunk = p*256 + tid; row = p*32 + (tid>>3),
    // dst col-chunk = tid&7; SOURCE col-chunk = (tid&7) ^ (row&7).
    const int r0 = tid >> 3;                       // 0..31
    const int cs = (((tid & 7) ^ (r0 & 7)) * 8);   // swizzled source col (f16)
    const f16* ag0 = A + (row0 +      r0) * lda + cs;
    const f16* ag1 = A + (row0 + 32 + r0) * lda + cs;
    const f16* ag2 = A + (row0 + 64 + r0) * lda + cs;
    const f16* ag3 = A + (row0 + 96 + r0) * lda + cs;
    const f16* bg0 = B + (col0 +      r0) * ldb + cs;
    const f16* bg1 = B + (col0 + 32 + r0) * ldb + cs;
    const f16* bg2 = B + (col0 + 64 + r0) * ldb + cs;
    const f16* bg3 = B + (col0 + 96 + r0) * ldb + cs;
    const int wofs = wave * 512;         // wave-uniform base within a pass

    // 4 waves in 2x2 -> each wave owns 64x64 = 4x4 MFMA tiles of 16x16.
    const int wm = wave >> 1, wn = wave & 1;
    const int fl = lane & 15;            // m (A) / n (B) within tile
    const int q  = lane >> 4;            // k-chunk
    // fragment read: row*64 + ((g ^ (row&7)) * 8); row&7 == fl&7.
    // kk=0: g=q -> co; kk=32: g=q+4=q^4 -> co^32.
    const int co = ((q ^ (fl & 7)) * 8);

    f32x4 acc[4][4] = {};

    const int niter = K >> 6;
    // preload iter 0 into buffer 0
    {
        f16* a = lA[0] + wofs;
        f16* b = lB[0] + wofs;
        gload16(ag0, a);        gload16(ag1, a + 2048);
        gload16(ag2, a + 4096); gload16(ag3, a + 6144);
        gload16(bg0, b);        gload16(bg1, b + 2048);
        gload16(bg2, b + 4096); gload16(bg3, b + 6144);
        ag0 += 64; ag1 += 64; ag2 += 64; ag3 += 64;
        bg0 += 64; bg1 += 64; bg2 += 64; bg3 += 64;
    }

    for (int it = 0; it < niter; ++it) {
        __syncthreads();   // drains loads(it) [issued one compute-phase ago]
        if (it + 1 < niter) {
            f16* a = lA[(it + 1) & 1] + wofs;
            f16* b = lB[(it + 1) & 1] + wofs;
            gload16(ag0, a);        gload16(ag1, a + 2048);
            gload16(ag2, a + 4096); gload16(ag3, a + 6144);
            gload16(bg0, b);        gload16(bg1, b + 2048);
            gload16(bg2, b + 4096); gload16(bg3, b + 6144);
            ag0 += 64; ag1 += 64; ag2 += 64; ag3 += 64;
            bg0 += 64; bg1 += 64; bg2 += 64; bg3 += 64;
        }
        const f16* paw = lA[it & 1] + (wm * 64 + fl) * 64;
        const f16* pbw = lB[it & 1] + (wn * 64 + fl) * 64;
#pragma unroll
        for (int kk = 0; kk < 64; kk += 32) {
            const int o = co ^ (kk == 0 ? 0 : 32);
            f16x8 a[4], b[4];
#pragma unroll
            for (int i = 0; i < 4; ++i)
                a[i] = *(const f16x8*)(paw + i * 1024 + o);
#pragma unroll
            for (int j = 0; j < 4; ++j)
                b[j] = *(const f16x8*)(pbw + j * 1024 + o);
#pragma unroll
            for (int i = 0; i < 4; ++i)
#pragma unroll
                for (int j = 0; j < 4; ++j)
                    acc[i][j] = __builtin_amdgcn_mfma_f32_16x16x32_f16(
                        a[i], b[j], acc[i][j], 0, 0, 0);
        }
    }

    // Epilogue: D[m][n], n = lane&15, m = (lane>>4)*4 + r
    const int rq = (lane >> 4) * 4;
    if (MODE != 0) R += (long)bz * 2048;
#pragma unroll
    for (int i = 0; i < 4; ++i) {
#pragma unroll
        for (int r = 0; r < 4; ++r) {
            const long row = row0 + wm * 64 + i * 16 + rq + r;
            if (MODE == 0) {
#pragma unroll
                for (int j = 0; j < 4; ++j) {
                    const long col = col0 + wn * 64 + j * 16 + fl;
                    C[row * ldc + col] = (OutT)acc[i][j][r];
                }
            } else if (MODE == 1) {
                float s = 0.f;
#pragma unroll
                for (int j = 0; j < 4; ++j) {
                    const long col = col0 + wn * 64 + j * 16 + fl;
                    float e = __expf(acc[i][j][r] * 0.125f - 12.0f);
                    C[row * ldc + col] = (OutT)e;
                    s += e;
                }
                s += __shfl_xor(s, 1, 16);
                s += __shfl_xor(s, 2, 16);
                s += __shfl_xor(s, 4, 16);
                s += __shfl_xor(s, 8, 16);
                if (fl == 0) atomicAdd(&R[row], s);
            } else {
                const float inv = 1.0f / R[row];
#pragma unroll
                for (int j = 0; j < 4; ++j) {
                    const long col = col0 + wn * 64 + j * 16 + fl;
                    C[row * ldc + col] = (OutT)(acc[i][j][r] * inv);
                }
            }
        }
    }
}

__global__ void cvt_f32_f16(const float* __restrict__ in, f16* __restrict__ out,
                            int n4)
{
    int i = blockIdx.x * blockDim.x + threadIdx.x;
    int stride = gridDim.x * blockDim.x;
    for (; i < n4; i += stride) {
        float4 v = ((const float4*)in)[i];
        f16x4 h;
        h[0] = (f16)v.x; h[1] = (f16)v.y; h[2] = (f16)v.z; h[3] = (f16)v.w;
        ((f16x4*)out)[i] = h;
    }
}

// wT[h][o][d] = f16(w[h][d][o]); grid (24, 24, 3), 256 threads (32x8 tile walk)
__global__ void wtrans(const float* __restrict__ w, f16* __restrict__ wT)
{
    __shared__ float t[32][33];
    const int h  = blockIdx.z;
    const int o0 = blockIdx.x * 32, d0 = blockIdx.y * 32;
    const int tx = threadIdx.x & 31, ty = threadIdx.x >> 5;
    const float* src = w + ((size_t)h * 768 + d0) * 768 + o0;
#pragma unroll
    for (int r = 0; r < 32; r += 8)
        t[ty + r][tx] = src[(size_t)(ty + r) * 768 + tx];
    __syncthreads();
    f16* dst = wT + ((size_t)h * 768 + o0) * 768 + d0;
#pragma unroll
    for (int r = 0; r < 32; r += 8)
        dst[(size_t)(ty + r) * 768 + tx] = (f16)t[tx][ty + r];
}

extern "C" void kernel_launch(void* const* d_in, const int* in_sizes, int n_in,
                              void* d_out, int out_size, void* d_ws, size_t ws_size,
                              hipStream_t stream)
{
    (void)in_sizes; (void)n_in; (void)out_size; (void)ws_size;
    const float* x = (const float*)d_in[0];
    const float* w = (const float*)d_in[1];
    float* out = (float*)d_out;

    // B=8, S=2048, D=O=768; BS = 16384
    const long NX = 12582912;      // 16384*768
    const long NW = 1769472;       // 3*768*768
    f16* xh  = (f16*)d_ws;         // [16384][768]   (dead after Vt GEMM)
    f16* wT  = xh + NX;            // [3][768][768]
    f16* QKh = wT + NW;            // [16384][1536]  (Q | K per row)
    f16* Vt  = QKh + 2 * NX;       // [8][768][2048]
    f16* Sc  = Vt + NX;            // [8][2048][2048]  exp-logits (unnormalized)
    float* R = (float*)xh;         // [8][2048] row sums — aliases dead xh
    // total ws: (4*NX + NW + 8*2048*2048) * 2 B = 171,311,104 B

    cvt_f32_f16<<<2048, 256, 0, stream>>>(x, xh, (int)(NX / 4));
    wtrans<<<dim3(24, 24, 3), 256, 0, stream>>>(w, wT);

    // QK = xh @ wT[0..1]^T   (M=16384, N=1536, K=768)
    gemm_bt<0, f16><<<dim3(12, 128, 1), 256, 0, stream>>>(
        xh, wT, QKh, nullptr, 768, 768, 768, 1536, 0, 0, 0);
    // Vt_b = wT2 @ xh_b^T    (M=768, N=2048, K=768), batched over 8
    gemm_bt<0, f16><<<dim3(16, 6, 8), 256, 0, stream>>>(
        wT + 1179648, xh, Vt, nullptr, 768, 768, 768, 2048, 0, 1572864, 1572864);
    // xh dead from here; R aliases it
    hipMemsetAsync(R, 0, 8 * 2048 * sizeof(float), stream);
    // Ps_b = exp(Q_b@K_b^T/8 - 12) + rowsum atomics  (M=2048, N=2048, K=768)
    gemm_bt<1, f16><<<dim3(16, 16, 8), 256, 0, stream>>>(
        QKh, QKh + 768, Sc, R, 768, 1536, 1536, 2048, 3145728, 3145728, 4194304);
    // out_b = (Ps_b @ Vt_b^T) / R[row]  (M=2048, N=768, K=2048), fp32 out
    gemm_bt<2, float><<<dim3(6, 16, 8), 256, 0, stream>>>(
        Sc, Vt, out, R, 2048, 2048, 2048, 768, 4194304, 1572864, 1572864);
}

// Round 7
// 326.692 us; speedup vs baseline: 1.0409x; 1.0409x over previous
//
#include <hip/hip_runtime.h>

// ---------------------------------------------------------------------------
// Self-attention, fp16-MFMA pipeline (R7: BK=32 double-buffer, 32 KB LDS):
//   xh   = fp16(x)                        [16384, 768]
//   wT   = fp16(kernel^T per head)        [3][768(o)][768(d)]
//   QKh  = xh @ wT[0..1]^T                [16384, 1536]  (Q | K per row)
//   Vt_b = wT2 @ xh_b^T   (per batch)     [8][768(o)][2048(t)]
//   Ps_b = exp(Q_b@K_b^T/8 - 12)          [8][2048, 2048] f16 (unnormalized)
//          + rowsum atomics -> R[8][2048]
//   out  = (Ps_b @ Vt_b^T) * (1/R[row])   [8][2048, 768]  fp32
//
// GEMM core: C = A @ B^T, 128x128 tile, BK=32, 16x16x32 MFMA, XCD remap.
// DOUBLE-BUFFERED at 2 x 8 KB per matrix = 32 KB total (same footprint as the
// single-buffered R5 -> occupancy preserved, unlike R6's 64 KB which dropped
// to 2 blocks/CU and regressed). One __syncthreads per K-iter; prefetch for
// iter k+1 issued right after the barrier, so the mandatory vmcnt(0) drain at
// the NEXT barrier waits on loads that had a full compute phase to land.
// LDS swizzle for 64 B rows: row r, 16B-chunk c holds global chunk
// c ^ ((r>>1)&3)  (rows alternate bank halves; key (r>>1)&3 spreads the quad
// lanes 2-per-bank-group = free 2-way). Applied on staging SOURCE address
// (global_load_lds dest must stay lane-contiguous) and on fragment reads;
// fragment rows are tile_base(mult of 16) + fl, so key = (fl>>1)&3.
// ---------------------------------------------------------------------------

typedef _Float16 f16;
typedef _Float16 f16x8 __attribute__((ext_vector_type(8)));
typedef _Float16 f16x4 __attribute__((ext_vector_type(4)));
typedef float f32x4 __attribute__((ext_vector_type(4)));

__device__ __forceinline__ void gload16(const void* g, void* l) {
    __builtin_amdgcn_global_load_lds((__attribute__((address_space(1))) void*)g,
                                     (__attribute__((address_space(3))) void*)l,
                                     16, 0, 0);
}

// MODE 0: C[row,col] = (OutT)acc
// MODE 1: C = f16(exp(acc/8 - 12)); atomicAdd row sums into R[bz*2048+row]
// MODE 2: C = (OutT)(acc / R[bz*2048+row])
template <int MODE, typename OutT>
__global__ __launch_bounds__(256, 2)
void gemm_bt(const f16* __restrict__ A, const f16* __restrict__ B,
             OutT* __restrict__ C, float* R, int K, int lda, int ldb, int ldc,
             long sA, long sB, long sC)
{
    __shared__ __align__(16) f16 lA[2][128 * 32];
    __shared__ __align__(16) f16 lB[2][128 * 32];

    const int tid  = threadIdx.x;
    const int wave = tid >> 6;
    const int lane = tid & 63;

    // XCD-aware remap (bijection when nb % 8 == 0; all our grids qualify)
    const unsigned gx = gridDim.x, gy = gridDim.y;
    const unsigned nb = gx * gy * gridDim.z;
    unsigned lin = blockIdx.x + gx * (blockIdx.y + gy * blockIdx.z);
    if ((nb & 7u) == 0u) lin = (lin & 7u) * (nb >> 3) + (lin >> 3);
    const unsigned bx = lin % gx;
    const unsigned rem = lin / gx;
    const unsigned by = rem % gy;
    const unsigned bz = rem / gy;

    A += (long)bz * sA;
    B += (long)bz * sB;
    C += (long)bz * sC;

    const long row0 = (long)by * 128;
    const long col0 = (long)bx * 128;

    // Staging (per matrix, per iter): 2 passes of 256 lanes.
    // Pass p: row = p*64 + (tid>>2), dst chunk = tid&3,
    // SOURCE chunk = (tid&3) ^ ((row>>1)&3) = (tid&3) ^ ((tid>>3)&3)
    // (p*64 contributes 0 mod 4 to row>>1). Dest addr16 = p*256 + w*64 + lane
    // -> lane-contiguous as global_load_lds requires.
    const int r0 = tid >> 2;                       // 0..63
    const int cs = (((tid & 3) ^ ((tid >> 3) & 3)) * 8);  // swizzled src col
    const f16* ag0 = A + (row0 +      r0) * lda + cs;
    const f16* ag1 = A + (row0 + 64 + r0) * lda + cs;
    const f16* bg0 = B + (col0 +      r0) * ldb + cs;
    const f16* bg1 = B + (col0 + 64 + r0) * ldb + cs;
    const int wofs = wave * 512;         // wave-uniform base (64 lanes * 16B)

    // 4 waves in 2x2 -> each wave owns 64x64 = 4x4 MFMA tiles of 16x16.
    const int wm = wave >> 1, wn = wave & 1;
    const int fl = lane & 15;            // m (A) / n (B) within tile
    const int q  = lane >> 4;            // k-chunk 0..3 (8 f16 each)
    // fragment read offset within row: (q ^ ((fl>>1)&3)) * 8 f16
    const int co = ((q ^ ((fl >> 1) & 3)) * 8);

    f32x4 acc[4][4] = {};

    const int niter = K >> 5;
    // preload iter 0 into buffer 0
    {
        f16* a = lA[0] + wofs;
        f16* b = lB[0] + wofs;
        gload16(ag0, a); gload16(ag1, a + 2048);
        gload16(bg0, b); gload16(bg1, b + 2048);
        ag0 += 32; ag1 += 32; bg0 += 32; bg1 += 32;
    }

    for (int it = 0; it < niter; ++it) {
        __syncthreads();   // drains loads(it) [issued one compute-phase ago]
        if (it + 1 < niter) {
            f16* a = lA[(it + 1) & 1] + wofs;
            f16* b = lB[(it + 1) & 1] + wofs;
            gload16(ag0, a); gload16(ag1, a + 2048);
            gload16(bg0, b); gload16(bg1, b + 2048);
            ag0 += 32; ag1 += 32; bg0 += 32; bg1 += 32;
        }
        const f16* paw = lA[it & 1] + (wm * 64 + fl) * 32 + co;
        const f16* pbw = lB[it & 1] + (wn * 64 + fl) * 32 + co;
        f16x8 a[4], b[4];
#pragma unroll
        for (int i = 0; i < 4; ++i)
            a[i] = *(const f16x8*)(paw + i * 512);
#pragma unroll
        for (int j = 0; j < 4; ++j)
            b[j] = *(const f16x8*)(pbw + j * 512);
#pragma unroll
        for (int i = 0; i < 4; ++i)
#pragma unroll
            for (int j = 0; j < 4; ++j)
                acc[i][j] = __builtin_amdgcn_mfma_f32_16x16x32_f16(
                    a[i], b[j], acc[i][j], 0, 0, 0);
    }

    // Epilogue: D[m][n], n = lane&15, m = (lane>>4)*4 + r
    const int rq = (lane >> 4) * 4;
    if (MODE != 0) R += (long)bz * 2048;
#pragma unroll
    for (int i = 0; i < 4; ++i) {
#pragma unroll
        for (int r = 0; r < 4; ++r) {
            const long row = row0 + wm * 64 + i * 16 + rq + r;
            if (MODE == 0) {
#pragma unroll
                for (int j = 0; j < 4; ++j) {
                    const long col = col0 + wn * 64 + j * 16 + fl;
                    C[row * ldc + col] = (OutT)acc[i][j][r];
                }
            } else if (MODE == 1) {
                float s = 0.f;
#pragma unroll
                for (int j = 0; j < 4; ++j) {
                    const long col = col0 + wn * 64 + j * 16 + fl;
                    float e = __expf(acc[i][j][r] * 0.125f - 12.0f);
                    C[row * ldc + col] = (OutT)e;
                    s += e;
                }
                s += __shfl_xor(s, 1, 16);
                s += __shfl_xor(s, 2, 16);
                s += __shfl_xor(s, 4, 16);
                s += __shfl_xor(s, 8, 16);
                if (fl == 0) atomicAdd(&R[row], s);
            } else {
                const float inv = 1.0f / R[row];
#pragma unroll
                for (int j = 0; j < 4; ++j) {
                    const long col = col0 + wn * 64 + j * 16 + fl;
                    C[row * ldc + col] = (OutT)(acc[i][j][r] * inv);
                }
            }
        }
    }
}

__global__ void cvt_f32_f16(const float* __restrict__ in, f16* __restrict__ out,
                            int n4)
{
    int i = blockIdx.x * blockDim.x + threadIdx.x;
    int stride = gridDim.x * blockDim.x;
    for (; i < n4; i += stride) {
        float4 v = ((const float4*)in)[i];
        f16x4 h;
        h[0] = (f16)v.x; h[1] = (f16)v.y; h[2] = (f16)v.z; h[3] = (f16)v.w;
        ((f16x4*)out)[i] = h;
    }
}

// wT[h][o][d] = f16(w[h][d][o]); grid (24, 24, 3), 256 threads (32x8 tile walk)
__global__ void wtrans(const float* __restrict__ w, f16* __restrict__ wT)
{
    __shared__ float t[32][33];
    const int h  = blockIdx.z;
    const int o0 = blockIdx.x * 32, d0 = blockIdx.y * 32;
    const int tx = threadIdx.x & 31, ty = threadIdx.x >> 5;
    const float* src = w + ((size_t)h * 768 + d0) * 768 + o0;
#pragma unroll
    for (int r = 0; r < 32; r += 8)
        t[ty + r][tx] = src[(size_t)(ty + r) * 768 + tx];
    __syncthreads();
    f16* dst = wT + ((size_t)h * 768 + o0) * 768 + d0;
#pragma unroll
    for (int r = 0; r < 32; r += 8)
        dst[(size_t)(ty + r) * 768 + tx] = (f16)t[tx][ty + r];
}

extern "C" void kernel_launch(void* const* d_in, const int* in_sizes, int n_in,
                              void* d_out, int out_size, void* d_ws, size_t ws_size,
                              hipStream_t stream)
{
    (void)in_sizes; (void)n_in; (void)out_size; (void)ws_size;
    const float* x = (const float*)d_in[0];
    const float* w = (const float*)d_in[1];
    float* out = (float*)d_out;

    // B=8, S=2048, D=O=768; BS = 16384
    const long NX = 12582912;      // 16384*768
    const long NW = 1769472;       // 3*768*768
    f16* xh  = (f16*)d_ws;         // [16384][768]   (dead after Vt GEMM)
    f16* wT  = xh + NX;            // [3][768][768]
    f16* QKh = wT + NW;            // [16384][1536]  (Q | K per row)
    f16* Vt  = QKh + 2 * NX;       // [8][768][2048]
    f16* Sc  = Vt + NX;            // [8][2048][2048]  exp-logits (unnormalized)
    float* R = (float*)xh;         // [8][2048] row sums — aliases dead xh
    // total ws: (4*NX + NW + 8*2048*2048) * 2 B = 171,311,104 B

    cvt_f32_f16<<<2048, 256, 0, stream>>>(x, xh, (int)(NX / 4));
    wtrans<<<dim3(24, 24, 3), 256, 0, stream>>>(w, wT);

    // QK = xh @ wT[0..1]^T   (M=16384, N=1536, K=768)
    gemm_bt<0, f16><<<dim3(12, 128, 1), 256, 0, stream>>>(
        xh, wT, QKh, nullptr, 768, 768, 768, 1536, 0, 0, 0);
    // Vt_b = wT2 @ xh_b^T    (M=768, N=2048, K=768), batched over 8
    gemm_bt<0, f16><<<dim3(16, 6, 8), 256, 0, stream>>>(
        wT + 1179648, xh, Vt, nullptr, 768, 768, 768, 2048, 0, 1572864, 1572864);
    // xh dead from here; R aliases it
    hipMemsetAsync(R, 0, 8 * 2048 * sizeof(float), stream);
    // Ps_b = exp(Q_b@K_b^T/8 - 12) + rowsum atomics  (M=2048, N=2048, K=768)
    gemm_bt<1, f16><<<dim3(16, 16, 8), 256, 0, stream>>>(
        QKh, QKh + 768, Sc, R, 768, 1536, 1536, 2048, 3145728, 3145728, 4194304);
    // out_b = (Ps_b @ Vt_b^T) / R[row]  (M=2048, N=768, K=2048), fp32 out
    gemm_bt<2, float><<<dim3(6, 16, 8), 256, 0, stream>>>(
        Sc, Vt, out, R, 2048, 2048, 2048, 768, 4194304, 1572864, 1572864);
}